// Round 5
// baseline (230.260 us; speedup 1.0000x reference)
//
#include <hip/hip_runtime.h>

// SSMBase: causal depthwise long conv + skip, bf16 MFMA block-Toeplitz.
// y[b,l,d] = sum_t k[d,t] x[b,l-t,d] + skip[d] x[b,l,d]
// x [4,4096,1024] f32, k [1024,4096] f32, skip [1024] f32.
// R4 (resubmit after infra failure): A-fragment via paired-b64 LDS layout
// (krevd) -> 2 loads not 4; transpose_x write-side full-line coalescing.

#define BB 4
#define LL 4096
#define DD 1024

typedef __attribute__((ext_vector_type(8))) short short8;
typedef __attribute__((ext_vector_type(16))) float f32x16;

__device__ __forceinline__ unsigned short f2bf(float f) {
    unsigned int u = __builtin_bit_cast(unsigned int, f);
    u += 0x7fffu + ((u >> 16) & 1u);
    return (unsigned short)(u >> 16);
}

// ---------------- transpose x: [B][L][D] f32 -> [B][D][L] bf16 ----------------
__global__ __launch_bounds__(256) void transpose_x_bf16(const float* __restrict__ in,
                                                        unsigned short* __restrict__ out) {
    __shared__ float tile[64][65];   // [d][l]
    int b = blockIdx.z;
    int d0 = blockIdx.x * 64;
    int l0 = blockIdx.y * 64;
    int tid = threadIdx.x;
    int u = tid & 15, v = tid >> 4;
#pragma unroll
    for (int rr = 0; rr < 4; rr++) {
        int l = v + 16 * rr;
        float4 t4 = *(const float4*)&in[((size_t)b * LL + l0 + l) * DD + d0 + 4 * u];
        tile[4 * u + 0][l] = t4.x;
        tile[4 * u + 1][l] = t4.y;
        tile[4 * u + 2][l] = t4.z;
        tile[4 * u + 3][l] = t4.w;
    }
    __syncthreads();
    // write: lane u3 = l-chunk, 8 lanes cover one d-row's 128B -> full lines/wave
    int u3 = tid & 7;
    int dd0 = tid >> 3;          // 0..31
#pragma unroll
    for (int it = 0; it < 2; it++) {
        int dd = dd0 + 32 * it;
        unsigned short pk[8];
#pragma unroll
        for (int e = 0; e < 8; e++) pk[e] = f2bf(tile[dd][8 * u3 + e]);
        *(uint4*)&out[((size_t)b * DD + d0 + dd) * LL + l0 + 8 * u3] =
            *(const uint4*)pk;
    }
}

// -------- transpose y + skip: out[b][l][d] = yt[b][d][l] + skip[d]*x[b][l][d] --------
__global__ __launch_bounds__(256) void transpose_y_skip(const float* __restrict__ yt,
                                                        const float* __restrict__ x,
                                                        const float* __restrict__ skip,
                                                        float* __restrict__ out) {
    __shared__ float tile[64][65];   // [l][d]
    int b = blockIdx.z;
    int d0 = blockIdx.x * 64;
    int l0 = blockIdx.y * 64;
    int tid = threadIdx.x;
    int u = tid & 15, v = tid >> 4;
#pragma unroll
    for (int rr = 0; rr < 4; rr++) {
        int dd = v + 16 * rr;
        float4 t4 = *(const float4*)&yt[((size_t)b * DD + d0 + dd) * LL + l0 + 4 * u];
        tile[4 * u + 0][dd] = t4.x;
        tile[4 * u + 1][dd] = t4.y;
        tile[4 * u + 2][dd] = t4.z;
        tile[4 * u + 3][dd] = t4.w;
    }
    __syncthreads();
    int ug = tid & 15, lr = tid >> 4;
    float4 sk4 = *(const float4*)&skip[d0 + 4 * ug];
#pragma unroll
    for (int rr = 0; rr < 4; rr++) {
        int l = lr + 16 * rr;
        size_t oi = ((size_t)b * LL + l0 + l) * DD + d0 + 4 * ug;
        float4 x4 = *(const float4*)&x[oi];
        float4 o4;
        o4.x = tile[l][4 * ug + 0] + sk4.x * x4.x;
        o4.y = tile[l][4 * ug + 1] + sk4.y * x4.y;
        o4.z = tile[l][4 * ug + 2] + sk4.z * x4.z;
        o4.w = tile[l][4 * ug + 3] + sk4.w * x4.w;
        *(float4*)&out[oi] = o4;
    }
}

// ---------------- conv: one block = one channel d, 8 waves ----------------
// A (Toeplitz k): lane needs words W(a0),W(a0+2),W(a0+4),W(a0+6),
//   W(u) = bf16(krev[u]) | bf16(krev[u+1])<<16, krev[j] = k[4095-j] (0 past end).
// krevd layout: krevd[2u] = W(u), krevd[2u+1] = W(u+2) -> fragment = two
//   8B-aligned uint2 reads at dwords 2a0 and 2a0+8 (mergeable ds_read2_b64).
// B (x): xbuf col c stride 80B (conflict-free b128), slot s=2q+h at +16s.
// Wave w owns tile pair p = (d&1)? 7-w : w -> tiles {2p,2p+1}; circular 8-slot
// B buffer: t1's operand at m == t0's fresh load at m-8.
__global__ __launch_bounds__(512, 4) void conv_mfma(
        const unsigned short* __restrict__ xt,  // [B][D][L] bf16
        const float* __restrict__ kw,           // [D][LL] f32
        float* __restrict__ yt) {               // [B][D][L] f32
    __shared__ unsigned int krevd[8256];        // 33 KB
    __shared__ unsigned char xbuf[43520];       // 544 cols * 80B
    const int tid = threadIdx.x;
    const int lane = tid & 63;
    const int w = tid >> 6;
    const int lam = lane & 31;
    const int h = lane >> 5;
    const int d = blockIdx.x;

    // stage krevd
    {
        const float* krow = kw + (size_t)d * LL;
        for (int u = tid; u < 4128; u += 512) {
            float a0f = (u     <= 4095) ? krow[4095 - u] : 0.f;
            float a1f = (u + 1 <= 4095) ? krow[4094 - u] : 0.f;
            float a2f = (u + 2 <= 4095) ? krow[4093 - u] : 0.f;
            float a3f = (u + 3 <= 4095) ? krow[4092 - u] : 0.f;
            unsigned int W0 = (unsigned int)f2bf(a0f) | ((unsigned int)f2bf(a1f) << 16);
            unsigned int W2 = (unsigned int)f2bf(a2f) | ((unsigned int)f2bf(a3f) << 16);
            krevd[2 * u]     = W0;
            krevd[2 * u + 1] = W2;
        }
    }
    // stage xbuf: col c = 4J+b, J=0..135 (8 zero-pad + 128 x-blocks)
    for (int sid = tid; sid < 2176; sid += 512) {
        int c = sid >> 2, sr = sid & 3;
        int J = c >> 2, b2 = c & 3;
        int ix = J - 8;
        uint4 v = {0u, 0u, 0u, 0u};
        if (ix >= 0)
            v = *(const uint4*)(xt + (((size_t)b2 * DD + d) * LL) + (ix << 5) + (sr << 3));
        *(uint4*)(xbuf + c * 80 + sr * 16) = v;
    }
    __syncthreads();

    const int p = (d & 1) ? (7 - w) : w;
    const int t0 = 2 * p, t1 = 2 * p + 1;
    const int nb = 2 * p + 2;

    f32x16 acc0, acc1;
#pragma unroll
    for (int i = 0; i < 16; i++) { acc0[i] = 0.f; acc1[i] = 0.f; }

#pragma unroll
    for (int q = 0; q < 2; ++q) {
        const int slot16 = (2 * q + h) * 16;
        const int abase = 4095 - lam + 8 * h + 16 * q;
        const unsigned char* xb = xbuf + lam * 80 + slot16;
        short8 buf[8];

#define LOAD_A(af, m)                                                          \
        short8 af;                                                             \
        {                                                                      \
            int a2 = (abase - ((m) << 5)) << 1;                                \
            uint2 p0 = *(const uint2*)&krevd[a2];                              \
            uint2 p1 = *(const uint2*)&krevd[a2 + 8];                          \
            struct U4 { unsigned int a, b, c, d; };                            \
            U4 au{p0.x, p0.y, p1.x, p1.y};                                     \
            af = __builtin_bit_cast(short8, au);                               \
        }

        // ---- first 8-block (m=0..7): fresh loads for BOTH tiles ----
#pragma unroll
        for (int j = 0; j < 8; ++j) {
            LOAD_A(af, j)
            short8 f0 = *(const short8*)(xb + (8 + 8 * t0 - j) * 320);
            short8 f1 = *(const short8*)(xb + (8 + 8 * t1 - j) * 320);
            acc0 = __builtin_amdgcn_mfma_f32_32x32x16_bf16(af, f0, acc0, 0, 0, 0);
            acc1 = __builtin_amdgcn_mfma_f32_32x32x16_bf16(af, f1, acc1, 0, 0, 0);
            buf[j] = f0;
        }
        // ---- middle blocks: 1 fresh load serves both tiles ----
        for (int blk = 1; blk <= nb - 2; ++blk) {
#pragma unroll
            for (int j = 0; j < 8; ++j) {
                int m = (blk << 3) + j;
                LOAD_A(af, m)
                short8 f0 = *(const short8*)(xb + (8 + 8 * t0 - m) * 320);
                acc1 = __builtin_amdgcn_mfma_f32_32x32x16_bf16(af, buf[j], acc1, 0, 0, 0);
                acc0 = __builtin_amdgcn_mfma_f32_32x32x16_bf16(af, f0, acc0, 0, 0, 0);
                buf[j] = f0;
            }
        }
        // ---- last 8-block: consume-only for t1 ----
#pragma unroll
        for (int j = 0; j < 8; ++j) {
            int m = ((nb - 1) << 3) + j;
            LOAD_A(af, m)
            acc1 = __builtin_amdgcn_mfma_f32_32x32x16_bf16(af, buf[j], acc1, 0, 0, 0);
        }
#undef LOAD_A
    }

    // ---- direct writeback: D layout col=lane&31, row=(reg&3)+8*(reg>>2)+4h ----
    const int b2 = lam & 3;
    const int j2 = lam >> 2;
#pragma unroll
    for (int tt = 0; tt < 2; ++tt) {
        int t = tt ? t1 : t0;
        const f32x16& ac = tt ? acc1 : acc0;
        int i = 8 * t + j2;
        float* base = yt + (((size_t)b2 * DD + d) * LL) + (i << 5) + 4 * h;
#pragma unroll
        for (int g = 0; g < 4; ++g) {
            float4 v = make_float4(ac[4 * g + 0], ac[4 * g + 1],
                                   ac[4 * g + 2], ac[4 * g + 3]);
            *(float4*)(base + 8 * g) = v;
        }
    }
}

// ---------------- fallback (ws too small): direct fp32 conv ----------------
#define NT 256
#define RPT 16
#define XS_PHYS 4368

__global__ __launch_bounds__(256) void conv_direct(
        const float* __restrict__ x_ld,
        const float* __restrict__ kw,
        const float* __restrict__ skip,
        float* __restrict__ out) {
    __shared__ float ks[LL];
    __shared__ float xs[XS_PHYS];
    int tid = threadIdx.x;
    int bid = blockIdx.x;
    int d = bid & (DD - 1);
    int b = bid >> 10;
    const float* krow = kw + (size_t)d * LL;
#pragma unroll
    for (int i = 0; i < LL; i += NT) ks[i + tid] = krow[i + tid];
    for (int i = tid; i < LL + 16; i += NT) {
        float v = (i < 16) ? 0.0f : x_ld[((size_t)b * LL + (i - 16)) * DD + d];
        xs[i + (i >> 4)] = v;
    }
    __syncthreads();
    float acc[RPT];
#pragma unroll
    for (int r = 0; r < RPT; r++) acc[r] = 0.0f;
#pragma unroll 1
    for (int c = 0; c <= tid; ++c) {
        int tt0 = c << 4;
        float kk[16];
#pragma unroll
        for (int j = 0; j < 16; j++) kk[j] = ks[tt0 + j];
        int pb = (tid - c) * 17 + 1;
        float xx[31];
#pragma unroll
        for (int u = 0; u < 31; u++) xx[u] = xs[pb + u + (u >= 15 ? 1 : 0)];
#pragma unroll
        for (int j = 0; j < 16; j++) {
#pragma unroll
            for (int r = 0; r < RPT; r++) acc[r] = fmaf(kk[j], xx[15 + r - j], acc[r]);
        }
    }
    float sk = skip[d];
    int pe = 17 * (tid + 1);
#pragma unroll
    for (int r = 0; r < RPT; r++) acc[r] = fmaf(sk, xs[pe + r], acc[r]);
    int l0 = tid << 4;
#pragma unroll
    for (int r = 0; r < RPT; r++)
        out[((size_t)b * LL + l0 + r) * DD + d] = acc[r];
}

extern "C" void kernel_launch(void* const* d_in, const int* in_sizes, int n_in,
                              void* d_out, int out_size, void* d_ws, size_t ws_size,
                              hipStream_t stream) {
    const float* x    = (const float*)d_in[0];
    const float* kw   = (const float*)d_in[1];
    const float* skip = (const float*)d_in[2];
    float* out = (float*)d_out;

    size_t xt_bytes = (size_t)BB * DD * LL * 2;   // 32 MB bf16
    size_t yt_bytes = (size_t)BB * DD * LL * 4;   // 64 MB f32

    if (ws_size >= xt_bytes + yt_bytes) {
        unsigned short* xt = (unsigned short*)d_ws;
        float* yt = (float*)((char*)d_ws + xt_bytes);
        transpose_x_bf16<<<dim3(DD / 64, LL / 64, BB), dim3(256), 0, stream>>>(x, xt);
        conv_mfma<<<dim3(DD), dim3(512), 0, stream>>>(xt, kw, yt);
        transpose_y_skip<<<dim3(DD / 64, LL / 64, BB), dim3(256), 0, stream>>>(yt, x, skip, out);
    } else {
        conv_direct<<<dim3(BB * DD), NT, 0, stream>>>(x, kw, skip, out);
    }
}